// Round 1
// baseline (226.185 us; speedup 1.0000x reference)
//
#include <hip/hip_runtime.h>

// SpikeFP32LayerNorm: LayerNorm (no affine) over rows of (8192, 4096) fp32,
// statistics + normalization emulated in FP64 per the reference circuit:
//   mean = sum(x64)/N ; c = x64 - mean ; var = sum(c*c)/N ; vpe = var + 1e-6
//   y = 1/vpe ; 5x NR: y = 0.5*y*(3 - vpe*y*y) ; out = fp32(c * y)
//
// Memory-bound: 268 MB total traffic -> ~45us floor at 6 TB/s.
// One 256-thread block per row; row (16 KiB) held in 16 VGPRs as float4[4].

#define LN_BATCH 8192
#define LN_N     4096
#define LN_THREADS 256
#define LN_EPS 1e-6

__global__ __launch_bounds__(LN_THREADS)
void spike_layernorm_kernel(const float* __restrict__ x, float* __restrict__ out) {
    const int row  = blockIdx.x;
    const int t    = threadIdx.x;
    const int wave = t >> 6;
    const int lane = t & 63;

    const float4* __restrict__ xr  = reinterpret_cast<const float4*>(x + (size_t)row * LN_N);
    float4* __restrict__       orow = reinterpret_cast<float4*>(out + (size_t)row * LN_N);

    // Load 16 elements per thread: 4 coalesced float4 loads, stride 256 lanes.
    float4 v[4];
#pragma unroll
    for (int i = 0; i < 4; ++i) v[i] = xr[t + i * LN_THREADS];

    // ---- Pass 1: FP64 sum -> mean ----
    double s = 0.0;
#pragma unroll
    for (int i = 0; i < 4; ++i)
        s += (double)v[i].x + (double)v[i].y + (double)v[i].z + (double)v[i].w;

#pragma unroll
    for (int off = 32; off > 0; off >>= 1) s += __shfl_down(s, off, 64);

    __shared__ double red[4];   // per-wave partials
    __shared__ double bcast[2]; // [0]=mean, [1]=y
    if (lane == 0) red[wave] = s;
    __syncthreads();
    if (t == 0) {
        double tot = red[0] + red[1] + red[2] + red[3];
        bcast[0] = tot * (1.0 / LN_N); // N = 4096 pow2: exact division
    }
    __syncthreads();
    const double mean = bcast[0];

    // ---- Pass 2: FP64 sum of c^2 -> var -> NR rsqrt ----
    double ss = 0.0;
#pragma unroll
    for (int i = 0; i < 4; ++i) {
        double d;
        d = (double)v[i].x - mean; ss += d * d;
        d = (double)v[i].y - mean; ss += d * d;
        d = (double)v[i].z - mean; ss += d * d;
        d = (double)v[i].w - mean; ss += d * d;
    }
#pragma unroll
    for (int off = 32; off > 0; off >>= 1) ss += __shfl_down(ss, off, 64);

    if (lane == 0) red[wave] = ss;
    __syncthreads();
    if (t == 0) {
        double var = (red[0] + red[1] + red[2] + red[3]) * (1.0 / LN_N);
        double vpe = var + LN_EPS;
        double y = 1.0 / vpe;               // seed: FP64 divide
#pragma unroll
        for (int it = 0; it < 5; ++it)      // 5 Newton-Raphson iterations
            y = 0.5 * y * (3.0 - vpe * (y * y));
        bcast[1] = y;
    }
    __syncthreads();
    const double y = bcast[1];

    // ---- Pass 3: out = fp32((x64 - mean) * y), coalesced float4 stores ----
#pragma unroll
    for (int i = 0; i < 4; ++i) {
        float4 o;
        o.x = (float)(((double)v[i].x - mean) * y);
        o.y = (float)(((double)v[i].y - mean) * y);
        o.z = (float)(((double)v[i].z - mean) * y);
        o.w = (float)(((double)v[i].w - mean) * y);
        orow[t + i * LN_THREADS] = o;
    }
}

extern "C" void kernel_launch(void* const* d_in, const int* in_sizes, int n_in,
                              void* d_out, int out_size, void* d_ws, size_t ws_size,
                              hipStream_t stream) {
    const float* x = (const float*)d_in[0];
    float* out = (float*)d_out;
    spike_layernorm_kernel<<<LN_BATCH, LN_THREADS, 0, stream>>>(x, out);
}

// Round 3
// 220.662 us; speedup vs baseline: 1.0250x; 1.0250x over previous
//
#include <hip/hip_runtime.h>

// SpikeFP32LayerNorm: LayerNorm (no affine) over rows of (8192, 4096) fp32,
// statistics + normalization in FP64 per the reference circuit:
//   mean = sum(x64)/N ; c = x64 - mean ; var = sum(c*c)/N ; vpe = var + 1e-6
//   y = 1/vpe ; 5x NR: y = 0.5*y*(3 - vpe*y*y) ; out = fp32(c * y)
//
// One WAVE per row (no barriers, no LDS): 64 lanes x 64 elements = 4096.
// Row held in 16 vec4 VGPRs; butterfly __shfl_xor allreduce; NR computed
// wave-uniformly on all lanes. Nontemporal loads/stores (stream-once data)
// via Clang ext_vector_type (HIP float4 is a struct -> builtin rejects it).

#define LN_BATCH 8192
#define LN_N     4096
#define LN_WPB   4                 // waves per block
#define LN_THREADS (LN_WPB * 64)
#define LN_F4PT  16                // vec4 per thread: 64 elems/lane
#define LN_EPS   1e-6

typedef float vfloat4 __attribute__((ext_vector_type(4)));

__device__ __forceinline__ double wave_allreduce_add(double s) {
#pragma unroll
    for (int off = 1; off < 64; off <<= 1)
        s += __shfl_xor(s, off, 64);
    return s;
}

__global__ __launch_bounds__(LN_THREADS)
void spike_layernorm_kernel(const float* __restrict__ x, float* __restrict__ out) {
    const int wave = threadIdx.x >> 6;
    const int lane = threadIdx.x & 63;
    const int row  = blockIdx.x * LN_WPB + wave;

    const vfloat4* __restrict__ xr =
        reinterpret_cast<const vfloat4*>(x + (size_t)row * LN_N);
    vfloat4* __restrict__ orow =
        reinterpret_cast<vfloat4*>(out + (size_t)row * LN_N);

    // 16 coalesced nontemporal vec4 loads, all in flight at once.
    vfloat4 v[LN_F4PT];
#pragma unroll
    for (int i = 0; i < LN_F4PT; ++i)
        v[i] = __builtin_nontemporal_load(&xr[lane + i * 64]);

    // ---- Pass 1: FP64 sum -> mean (4 independent accumulators) ----
    double s0 = 0.0, s1 = 0.0, s2 = 0.0, s3 = 0.0;
#pragma unroll
    for (int i = 0; i < LN_F4PT; i += 4) {
        s0 += (double)v[i + 0].x + (double)v[i + 0].y + (double)v[i + 0].z + (double)v[i + 0].w;
        s1 += (double)v[i + 1].x + (double)v[i + 1].y + (double)v[i + 1].z + (double)v[i + 1].w;
        s2 += (double)v[i + 2].x + (double)v[i + 2].y + (double)v[i + 2].z + (double)v[i + 2].w;
        s3 += (double)v[i + 3].x + (double)v[i + 3].y + (double)v[i + 3].z + (double)v[i + 3].w;
    }
    const double mean = wave_allreduce_add((s0 + s1) + (s2 + s3)) * (1.0 / LN_N);

    // ---- Pass 2: FP64 sum of (x-mean)^2 -> var -> NR rsqrt (wave-uniform) ----
    double q0 = 0.0, q1 = 0.0, q2 = 0.0, q3 = 0.0;
#pragma unroll
    for (int i = 0; i < LN_F4PT; i += 4) {
        double d;
        d = (double)v[i + 0].x - mean; q0 += d * d;
        d = (double)v[i + 0].y - mean; q0 += d * d;
        d = (double)v[i + 0].z - mean; q0 += d * d;
        d = (double)v[i + 0].w - mean; q0 += d * d;
        d = (double)v[i + 1].x - mean; q1 += d * d;
        d = (double)v[i + 1].y - mean; q1 += d * d;
        d = (double)v[i + 1].z - mean; q1 += d * d;
        d = (double)v[i + 1].w - mean; q1 += d * d;
        d = (double)v[i + 2].x - mean; q2 += d * d;
        d = (double)v[i + 2].y - mean; q2 += d * d;
        d = (double)v[i + 2].z - mean; q2 += d * d;
        d = (double)v[i + 2].w - mean; q2 += d * d;
        d = (double)v[i + 3].x - mean; q3 += d * d;
        d = (double)v[i + 3].y - mean; q3 += d * d;
        d = (double)v[i + 3].z - mean; q3 += d * d;
        d = (double)v[i + 3].w - mean; q3 += d * d;
    }
    const double var = wave_allreduce_add((q0 + q1) + (q2 + q3)) * (1.0 / LN_N);

    const double vpe = var + LN_EPS;
    double y = 1.0 / vpe;               // FP64 divide seed (uniform across lanes)
#pragma unroll
    for (int it = 0; it < 5; ++it)      // 5 Newton-Raphson iterations
        y = 0.5 * y * (3.0 - vpe * (y * y));

    // ---- Pass 3: out = fp32((x64 - mean) * y), nontemporal vec4 stores ----
#pragma unroll
    for (int i = 0; i < LN_F4PT; ++i) {
        vfloat4 o;
        o.x = (float)(((double)v[i].x - mean) * y);
        o.y = (float)(((double)v[i].y - mean) * y);
        o.z = (float)(((double)v[i].z - mean) * y);
        o.w = (float)(((double)v[i].w - mean) * y);
        __builtin_nontemporal_store(o, &orow[lane + i * 64]);
    }
}

extern "C" void kernel_launch(void* const* d_in, const int* in_sizes, int n_in,
                              void* d_out, int out_size, void* d_ws, size_t ws_size,
                              hipStream_t stream) {
    const float* x = (const float*)d_in[0];
    float* out = (float*)d_out;
    spike_layernorm_kernel<<<LN_BATCH / LN_WPB, LN_THREADS, 0, stream>>>(x, out);
}